// Round 14
// baseline (515.575 us; speedup 1.0000x reference)
//
#include <hip/hip_runtime.h>
#include <hip/hip_bf16.h>
#include <cstdint>
#include <cstddef>

// CFnetFilter: w_ij = segment_sum(ssp(ssp(dijk@W1+b1)@W2+b2), seg_j)
//
// R14 = R12 (423us; R13's intra-block pipeline was a clean null) with the
// DS-pipe diet. R12 audit: each 16-col wave read the ENTIRE 32KB A-tile per
// GEMM -> 512KB LDS-read per block (~157us of DS pipe, the top pipe).
//  (a) mfma_f32_32x32x16_bf16 with 32-col waves: wave = (col-slice of 32,
//      row-half of 64). A-read amplification 8x -> 4x (256KB/block); MFMA
//      count halves (16/layer/wave); higher FLOP/cyc.
//  (b) 4-bit XOR swizzle ((row&15)<<4, bijective in the 256B row): A-reads
//      spread 32 rows over 16 bank-slots -> 2-way (free) vs 4-way before.
//  (c) B-frags loaded in two halves of 4 (reg budget: acc 32 + bf 16 + addr
//      ~20 <= 85 at __launch_bounds__(512,6), 3 blocks/CU unchanged).

typedef float  f32x4  __attribute__((ext_vector_type(4)));
typedef float  f32x16 __attribute__((ext_vector_type(16)));
typedef __bf16 bf16x8 __attribute__((ext_vector_type(8)));

// may_alias views for LDS type-punning (R5 lesson)
typedef uint32_t u32a    __attribute__((may_alias));
typedef bf16x8   bf16x8a __attribute__((may_alias));
typedef __bf16   bf16a   __attribute__((may_alias));

static constexpr int   N_TRIPLES = 2000000;
static constexpr int   DIM       = 128;
static constexpr int   NSEG      = 100000;
static constexpr int   ROWS      = 128;     // rows per block (2e6 / 128 exact)
static constexpr float LOG2F_    = 0.6931471805599453f;   // ln2
static constexpr float LOG2E_    = 1.4426950408889634f;   // 1/ln2

// base-2 softplus core: u = max(y,0) + log2(1 + 2^-|y|)
__device__ __forceinline__ float sp2_(float y) {
  float t = __builtin_amdgcn_exp2f(-__builtin_fabsf(y));   // v_exp with -abs mods
  return fmaxf(y, 0.0f) + __builtin_amdgcn_logf(1.0f + t); // v_log = log2
}

// WT1 = (W1*log2e)^T bf16 ; WT2 = W2^T bf16  (B-frags contiguous in k)
__global__ void wt_kernel(const float* __restrict__ W1, const float* __restrict__ W2,
                          __bf16* __restrict__ WT) {
  int t = blockIdx.x * 256 + threadIdx.x;   // 0..16383
  int k = t >> 7;
  int n = t & 127;
  WT[n * 128 + k]         = (__bf16)(W1[t] * LOG2E_);
  WT[16384 + n * 128 + k] = (__bf16)W2[t];
}

// b1p[n] = b1[n]*log2e ;  b2p[n] = (b2[n] - ln2*sum_k W2[k][n]) * log2e
__global__ void bias_kernel(const float* __restrict__ b1, const float* __restrict__ W2,
                            const float* __restrict__ b2,
                            float* __restrict__ b1p, float* __restrict__ b2p) {
  int n = threadIdx.x;
  float s = 0.0f;
  #pragma unroll 8
  for (int k = 0; k < 128; ++k) s += W2[k * 128 + n];
  b1p[n] = b1[n] * LOG2E_;
  b2p[n] = (b2[n] - LOG2F_ * s) * LOG2E_;
}

__global__ __launch_bounds__(512, 6) void fused_kernel(
    const float* __restrict__ dijk, const int* __restrict__ seg,
    const __bf16* __restrict__ WT,
    const float* __restrict__ b1v, const float* __restrict__ b2p,
    float* __restrict__ out)
{
  __shared__ __bf16 tile[ROWS * DIM];   // 32 KB: A, then u1, then wijk

  const int tid  = threadIdx.x;         // 0..511
  const int lane = tid & 63;
  const int wave = tid >> 6;            // 0..7
  const int l31  = lane & 31;
  const int h5   = lane >> 5;           // k-half within the wave
  const int cs   = wave & 3;            // col slice [32cs, 32cs+32)
  const int rh   = wave >> 2;           // row half: rows [64rh, 64rh+64)
  const int r0   = blockIdx.x * ROWS;

  char* tb = (char*)tile;

  // ---- phase 0: stage A = bf16(dijk rows) -> LDS (4-bit swizzle) ----
  {
    int row = tid >> 2, q = tid & 3;
    const float* src = dijk + (size_t)(r0 + row) * DIM + q * 32;
    char* dst = tb + row * 256;
    int swz = (row & 15) << 4;
    #pragma unroll
    for (int u = 0; u < 4; ++u) {
      f32x4 v0 = *(const f32x4*)(src + u * 8);
      f32x4 v1 = *(const f32x4*)(src + u * 8 + 4);
      bf16x8 t8;
      t8[0] = (__bf16)v0[0]; t8[1] = (__bf16)v0[1]; t8[2] = (__bf16)v0[2]; t8[3] = (__bf16)v0[3];
      t8[4] = (__bf16)v1[0]; t8[5] = (__bf16)v1[1]; t8[6] = (__bf16)v1[2]; t8[7] = (__bf16)v1[3];
      *(bf16x8a*)(dst + ((q * 64 + u * 16) ^ swz)) = t8;
    }
  }

  const int colw = cs * 32 + l31;       // this lane's output column
  const float bias1 = b1v[colw];
  const float bias2 = b2p[colw];

  // hoisted addressing:
  // A-frag (32x32x16): m = l31, k = h5*8 + j; row(t) = rh*64 + t*32 + l31
  // (row&15 = l31&15, t-invariant). byte = row*256 + ((ks*32 + h5*16) ^ swz)
  const int  swzA = (l31 & 15) << 4;
  const char* abase = tb + (rh * 64 + l31) * 256;   // t adds 8192
  uint32_t bo[8];
  #pragma unroll
  for (int ks = 0; ks < 8; ++ks) bo[ks] = (uint32_t)((ks * 32 + h5 * 16) ^ swzA);
  // C/D (32x32): col = l31, row = rh*64 + t*32 + (reg&3) + 8*(reg>>2) + 4*h5
  // store byte = row*256 + ((colw*2) ^ ((row&15)<<4)); (row&15) = 8*(q&1)+4*h5+j
  const uint32_t wrow0 = (uint32_t)((rh * 64 + 4 * h5) * 256);
  uint32_t e0[4];
  #pragma unroll
  for (int j = 0; j < 4; ++j)
    e0[j] = (uint32_t)((colw * 2) ^ ((4 * h5 + j) << 4));

  __syncthreads();   // [1] A-tile staged

  // ---- phase 1: GEMM1 (reads A) ----
  f32x16 acc0 = {}, acc1 = {};
  #pragma unroll
  for (int ksh = 0; ksh < 2; ++ksh) {
    bf16x8 bf[4];
    #pragma unroll
    for (int i = 0; i < 4; ++i)
      bf[i] = *(const bf16x8*)(WT + colw * 128 + (ksh * 4 + i) * 16 + h5 * 8);
    #pragma unroll
    for (int i = 0; i < 4; ++i) {
      bf16x8 a0 = *(const bf16x8a*)(abase + bo[ksh * 4 + i]);
      bf16x8 a1 = *(const bf16x8a*)(abase + 8192 + bo[ksh * 4 + i]);
      acc0 = __builtin_amdgcn_mfma_f32_32x32x16_bf16(a0, bf[i], acc0, 0, 0, 0);
      acc1 = __builtin_amdgcn_mfma_f32_32x32x16_bf16(a1, bf[i], acc1, 0, 0, 0);
    }
  }

  __syncthreads();   // [2] all A-reads done -> tile reusable for u1

  // ---- phase 2: u1 = sp2(y1) -> tile ----
  {
    auto spstore1 = [&](const f32x16& a, uint32_t tof) {
      #pragma unroll
      for (int q = 0; q < 4; ++q) {
        #pragma unroll
        for (int j = 0; j < 4; ++j) {
          float u1 = sp2_(a[q * 4 + j] + bias1);
          uint32_t off = wrow0 + tof + (uint32_t)(q * 2048 + j * 256)
                       + (e0[j] ^ ((uint32_t)(q & 1) << 7));
          *(bf16a*)(tb + off) = (__bf16)u1;
        }
      }
    };
    spstore1(acc0, 0);
    spstore1(acc1, 8192);
  }

  __syncthreads();   // [3] u1 complete

  // ---- phase 3: GEMM2 (reads u1; W2 unscaled since ln2*log2e = 1) ----
  acc0 = (f32x16){}; acc1 = (f32x16){};
  #pragma unroll
  for (int ksh = 0; ksh < 2; ++ksh) {
    bf16x8 bf[4];
    #pragma unroll
    for (int i = 0; i < 4; ++i)
      bf[i] = *(const bf16x8*)(WT + 16384 + colw * 128 + (ksh * 4 + i) * 16 + h5 * 8);
    #pragma unroll
    for (int i = 0; i < 4; ++i) {
      bf16x8 a0 = *(const bf16x8a*)(abase + bo[ksh * 4 + i]);
      bf16x8 a1 = *(const bf16x8a*)(abase + 8192 + bo[ksh * 4 + i]);
      acc0 = __builtin_amdgcn_mfma_f32_32x32x16_bf16(a0, bf[i], acc0, 0, 0, 0);
      acc1 = __builtin_amdgcn_mfma_f32_32x32x16_bf16(a1, bf[i], acc1, 0, 0, 0);
    }
  }

  __syncthreads();   // [4] all u1-reads done -> tile reusable for wijk

  // ---- phase 4: w = fma(sp2(y2), ln2, -ln2) -> tile ----
  {
    auto spstore2 = [&](const f32x16& a, uint32_t tof) {
      #pragma unroll
      for (int q = 0; q < 4; ++q) {
        #pragma unroll
        for (int j = 0; j < 4; ++j) {
          float u2 = sp2_(a[q * 4 + j] + bias2);
          float wv = __builtin_fmaf(u2, LOG2F_, -LOG2F_);
          uint32_t off = wrow0 + tof + (uint32_t)(q * 2048 + j * 256)
                       + (e0[j] ^ ((uint32_t)(q & 1) << 7));
          *(bf16a*)(tb + off) = (__bf16)wv;
        }
      }
    };
    spstore2(acc0, 0);
    spstore2(acc1, 8192);
  }

  __syncthreads();   // [5] wijk complete, visible to all

  // ---- phase 5: segmented reduce (paired-column u32 form, swz16) ----
  // thread: col pair colb = (tid&63)*2, row group hh = tid>>6 -> 16 rows.
  {
    const int colb = (tid & 63) * 2;
    const int hh   = tid >> 6;           // 0..7
    const int rbeg = hh * 16;            // multiple of 16 -> row&15 = i
    const int* sp = seg + r0;
    const char* rbase = tb + rbeg * 256;
    const uint32_t cx = (uint32_t)(colb * 2);
    float a0 = 0.0f, a1 = 0.0f;
    int cur = sp[rbeg];
    #pragma unroll
    for (int i = 0; i < 16; ++i) {
      int s = sp[rbeg + i];
      if (s != cur) {
        atomicAdd(out + (size_t)cur * DIM + colb,     a0);
        atomicAdd(out + (size_t)cur * DIM + colb + 1, a1);
        a0 = 0.0f; a1 = 0.0f; cur = s;
      }
      uint32_t w = *(const u32a*)(rbase + i * 256 + (cx ^ (uint32_t)(i << 4)));
      a0 += __uint_as_float(w << 16);          // bf16 lo -> f32
      a1 += __uint_as_float(w & 0xffff0000u);  // bf16 hi -> f32
    }
    atomicAdd(out + (size_t)cur * DIM + colb,     a0);
    atomicAdd(out + (size_t)cur * DIM + colb + 1, a1);
  }
}

extern "C" void kernel_launch(void* const* d_in, const int* in_sizes, int n_in,
                              void* d_out, int out_size, void* d_ws, size_t ws_size,
                              hipStream_t stream) {
  const float* dijk = (const float*)d_in[0];
  const int*   seg  = (const int*)d_in[1];
  const float* W1   = (const float*)d_in[2];
  const float* b1   = (const float*)d_in[3];
  const float* W2   = (const float*)d_in[4];
  const float* b2   = (const float*)d_in[5];
  float* out = (float*)d_out;

  float*  b1p = (float*)d_ws;                       // 128 f32
  float*  b2p = (float*)((char*)d_ws + 512);        // 128 f32
  __bf16* WT  = (__bf16*)((char*)d_ws + 1024);      // 2 * 128*128 bf16 = 64 KB

  // empty segments must be exactly 0; memset re-zeroes every replay
  (void)hipMemsetAsync(out, 0, (size_t)NSEG * DIM * sizeof(float), stream);

  wt_kernel<<<64, 256, 0, stream>>>(W1, W2, WT);
  bias_kernel<<<1, 128, 0, stream>>>(b1, W2, b2, b1p, b2p);

  fused_kernel<<<N_TRIPLES / ROWS, 512, 0, stream>>>(dijk, seg, WT, b1p, b2p, out);
}

// Round 15
// 489.463 us; speedup vs baseline: 1.0533x; 1.0533x over previous
//
#include <hip/hip_runtime.h>
#include <hip/hip_bf16.h>
#include <cstdint>
#include <cstddef>

// CFnetFilter: w_ij = segment_sum(ssp(ssp(dijk@W1+b1)@W2+b2), seg_j)
//
// R15 = R12 (423us) with ONLY the wave->output decomposition changed:
// wave = (32-col slice, 64-row half) instead of (16-col, 128-row).
// Each A-frag ds_read_b128 now feeds TWO 16x16x32 MFMAs (nt=0,1) -> GEMM
// A-reads per block halve (512 -> 256 wave-insts), attacking the DS pipe
// (modeled ~73% of R12's wall). MFMA shape/count, 3-bit swizzle, staging,
// softplus diet, and reduce are all R12-verbatim. R14's 32x32 variant
// regressed from side costs; this is the minimal-diff version of the lever.

typedef float  f32x4  __attribute__((ext_vector_type(4)));
typedef __bf16 bf16x8 __attribute__((ext_vector_type(8)));

// may_alias views for LDS type-punning (R5 lesson)
typedef uint32_t u32a    __attribute__((may_alias));
typedef bf16x8   bf16x8a __attribute__((may_alias));
typedef __bf16   bf16a   __attribute__((may_alias));

static constexpr int   N_TRIPLES = 2000000;
static constexpr int   DIM       = 128;
static constexpr int   NSEG      = 100000;
static constexpr int   ROWS      = 128;     // rows per block (2e6 / 128 exact)
static constexpr float LOG2F_    = 0.6931471805599453f;   // ln2
static constexpr float LOG2E_    = 1.4426950408889634f;   // 1/ln2

// base-2 softplus core: u = max(y,0) + log2(1 + 2^-|y|)
__device__ __forceinline__ float sp2_(float y) {
  float t = __builtin_amdgcn_exp2f(-__builtin_fabsf(y));   // v_exp with -abs mods
  return fmaxf(y, 0.0f) + __builtin_amdgcn_logf(1.0f + t); // v_log = log2
}

// WT1 = (W1*log2e)^T bf16 ; WT2 = W2^T bf16  (B-frags contiguous in k)
__global__ void wt_kernel(const float* __restrict__ W1, const float* __restrict__ W2,
                          __bf16* __restrict__ WT) {
  int t = blockIdx.x * 256 + threadIdx.x;   // 0..16383
  int k = t >> 7;
  int n = t & 127;
  WT[n * 128 + k]         = (__bf16)(W1[t] * LOG2E_);
  WT[16384 + n * 128 + k] = (__bf16)W2[t];
}

// b1p[n] = b1[n]*log2e ;  b2p[n] = (b2[n] - ln2*sum_k W2[k][n]) * log2e
__global__ void bias_kernel(const float* __restrict__ b1, const float* __restrict__ W2,
                            const float* __restrict__ b2,
                            float* __restrict__ b1p, float* __restrict__ b2p) {
  int n = threadIdx.x;
  float s = 0.0f;
  #pragma unroll 8
  for (int k = 0; k < 128; ++k) s += W2[k * 128 + n];
  b1p[n] = b1[n] * LOG2E_;
  b2p[n] = (b2[n] - LOG2F_ * s) * LOG2E_;
}

__global__ __launch_bounds__(512, 6) void fused_kernel(
    const float* __restrict__ dijk, const int* __restrict__ seg,
    const __bf16* __restrict__ WT,
    const float* __restrict__ b1v, const float* __restrict__ b2p,
    float* __restrict__ out)
{
  __shared__ __bf16 tile[ROWS * DIM];   // 32 KB: A, then u1, then wijk

  const int tid  = threadIdx.x;         // 0..511
  const int lane = tid & 63;
  const int wave = tid >> 6;            // 0..7
  const int l15  = lane & 15;
  const int g    = lane >> 4;           // k-group
  const int cs   = wave & 3;            // col slice [32cs, 32cs+32)
  const int rh   = wave >> 2;           // row half [64rh, 64rh+64)
  const int r0   = blockIdx.x * ROWS;

  char* tb = (char*)tile;

  // ---- phase 0: stage A = bf16(dijk rows) -> LDS (swizzled), cooperative ----
  {
    int row = tid >> 2, q = tid & 3;
    const float* src = dijk + (size_t)(r0 + row) * DIM + q * 32;
    char* dst = tb + row * 256;
    int swz = (row & 7) << 4;
    #pragma unroll
    for (int u = 0; u < 4; ++u) {
      f32x4 v0 = *(const f32x4*)(src + u * 8);
      f32x4 v1 = *(const f32x4*)(src + u * 8 + 4);
      bf16x8 t8;
      t8[0] = (__bf16)v0[0]; t8[1] = (__bf16)v0[1]; t8[2] = (__bf16)v0[2]; t8[3] = (__bf16)v0[3];
      t8[4] = (__bf16)v1[0]; t8[5] = (__bf16)v1[1]; t8[6] = (__bf16)v1[2]; t8[7] = (__bf16)v1[3];
      *(bf16x8a*)(dst + ((q * 64 + u * 16) ^ swz)) = t8;
    }
  }

  // this lane's two output columns (nt = 0, 1)
  const int col0 = cs * 32 + l15;
  const int col1 = col0 + 16;
  const float bias1_0 = b1v[col0], bias1_1 = b1v[col1];
  const float bias2_0 = b2p[col0], bias2_1 = b2p[col1];

  // hoisted addressing:
  // A-reads: row = rh*64 + mt*16 + l15 (row&7 = l15&7, mt-invariant)
  const int  swA = (l15 & 7) << 4;
  const char* abase = tb + (rh * 64 + l15) * 256;     // + mt*4096
  uint32_t bo[4];
  #pragma unroll
  for (int ks = 0; ks < 4; ++ks) bo[ks] = (uint32_t)((ks * 64 + g * 16) ^ swA);
  // sp-stores: row = rh*64 + mt*16 + g*4 + j (row&7 = (g*4+j)&7)
  uint32_t wb[2][4];
  #pragma unroll
  for (int j = 0; j < 4; ++j) {
    int rj = g * 4 + j;
    uint32_t rbyte = (uint32_t)(rh * 64 + rj) * 256;
    wb[0][j] = rbyte + (uint32_t)((col0 * 2) ^ ((rj & 7) << 4));
    wb[1][j] = rbyte + (uint32_t)((col1 * 2) ^ ((rj & 7) << 4));
  }

  __syncthreads();   // [1] A-tile complete

  // ---- phase 1: GEMM1 (each A-frag feeds both nt-tiles) ----
  f32x4 acc[4][2];
  #pragma unroll
  for (int mt = 0; mt < 4; ++mt) {
    acc[mt][0] = (f32x4){0.f, 0.f, 0.f, 0.f};
    acc[mt][1] = (f32x4){0.f, 0.f, 0.f, 0.f};
  }
  #pragma unroll
  for (int ks = 0; ks < 4; ++ks) {
    bf16x8 b0 = *(const bf16x8*)(WT + col0 * 128 + ks * 32 + g * 8);
    bf16x8 b1 = *(const bf16x8*)(WT + col1 * 128 + ks * 32 + g * 8);
    #pragma unroll
    for (int mt = 0; mt < 4; ++mt) {
      bf16x8 a = *(const bf16x8a*)(abase + mt * 4096 + bo[ks]);
      acc[mt][0] = __builtin_amdgcn_mfma_f32_16x16x32_bf16(a, b0, acc[mt][0], 0, 0, 0);
      acc[mt][1] = __builtin_amdgcn_mfma_f32_16x16x32_bf16(a, b1, acc[mt][1], 0, 0, 0);
    }
  }

  __syncthreads();   // [2] all A-reads done -> tile reusable for u1

  // ---- phase 2: u1 = sp2(y1) -> tile ----
  #pragma unroll
  for (int mt = 0; mt < 4; ++mt) {
    #pragma unroll
    for (int j = 0; j < 4; ++j) {
      float u1a = sp2_(acc[mt][0][j] + bias1_0);
      float u1b = sp2_(acc[mt][1][j] + bias1_1);
      *(bf16a*)(tb + wb[0][j] + mt * 4096) = (__bf16)u1a;
      *(bf16a*)(tb + wb[1][j] + mt * 4096) = (__bf16)u1b;
    }
  }

  __syncthreads();   // [3] u1 complete

  // ---- phase 3: GEMM2 (reads u1; W2 unscaled since ln2*log2e = 1) ----
  f32x4 acc2[4][2];
  #pragma unroll
  for (int mt = 0; mt < 4; ++mt) {
    acc2[mt][0] = (f32x4){0.f, 0.f, 0.f, 0.f};
    acc2[mt][1] = (f32x4){0.f, 0.f, 0.f, 0.f};
  }
  #pragma unroll
  for (int ks = 0; ks < 4; ++ks) {
    bf16x8 b0 = *(const bf16x8*)(WT + 16384 + col0 * 128 + ks * 32 + g * 8);
    bf16x8 b1 = *(const bf16x8*)(WT + 16384 + col1 * 128 + ks * 32 + g * 8);
    #pragma unroll
    for (int mt = 0; mt < 4; ++mt) {
      bf16x8 a = *(const bf16x8a*)(abase + mt * 4096 + bo[ks]);
      acc2[mt][0] = __builtin_amdgcn_mfma_f32_16x16x32_bf16(a, b0, acc2[mt][0], 0, 0, 0);
      acc2[mt][1] = __builtin_amdgcn_mfma_f32_16x16x32_bf16(a, b1, acc2[mt][1], 0, 0, 0);
    }
  }

  __syncthreads();   // [4] all u1-reads done -> tile reusable for wijk

  // ---- phase 4: w = fma(sp2(y2), ln2, -ln2) -> tile ----
  #pragma unroll
  for (int mt = 0; mt < 4; ++mt) {
    #pragma unroll
    for (int j = 0; j < 4; ++j) {
      float u2a = sp2_(acc2[mt][0][j] + bias2_0);
      float u2b = sp2_(acc2[mt][1][j] + bias2_1);
      *(bf16a*)(tb + wb[0][j] + mt * 4096) = (__bf16)__builtin_fmaf(u2a, LOG2F_, -LOG2F_);
      *(bf16a*)(tb + wb[1][j] + mt * 4096) = (__bf16)__builtin_fmaf(u2b, LOG2F_, -LOG2F_);
    }
  }

  __syncthreads();   // [5] wijk complete, visible to all

  // ---- phase 5: segmented reduce (R12-verbatim, paired-column u32 form) ----
  {
    const int colb = (tid & 63) * 2;
    const int hh   = tid >> 6;           // 0..7
    const int rbeg = hh * 16;
    const int* sp = seg + r0;
    const char* rp[8];
    #pragma unroll
    for (int k = 0; k < 8; ++k)
      rp[k] = tb + rbeg * 256 + ((colb * 2) ^ (k << 4));
    float a0 = 0.0f, a1 = 0.0f;
    int cur = sp[rbeg];
    #pragma unroll
    for (int i = 0; i < 16; ++i) {
      int s = sp[rbeg + i];
      if (s != cur) {
        atomicAdd(out + (size_t)cur * DIM + colb,     a0);
        atomicAdd(out + (size_t)cur * DIM + colb + 1, a1);
        a0 = 0.0f; a1 = 0.0f; cur = s;
      }
      uint32_t w = *(const u32a*)(rp[i & 7] + i * 256);
      a0 += __uint_as_float(w << 16);          // bf16 lo -> f32
      a1 += __uint_as_float(w & 0xffff0000u);  // bf16 hi -> f32
    }
    atomicAdd(out + (size_t)cur * DIM + colb,     a0);
    atomicAdd(out + (size_t)cur * DIM + colb + 1, a1);
  }
}

extern "C" void kernel_launch(void* const* d_in, const int* in_sizes, int n_in,
                              void* d_out, int out_size, void* d_ws, size_t ws_size,
                              hipStream_t stream) {
  const float* dijk = (const float*)d_in[0];
  const int*   seg  = (const int*)d_in[1];
  const float* W1   = (const float*)d_in[2];
  const float* b1   = (const float*)d_in[3];
  const float* W2   = (const float*)d_in[4];
  const float* b2   = (const float*)d_in[5];
  float* out = (float*)d_out;

  float*  b1p = (float*)d_ws;                       // 128 f32
  float*  b2p = (float*)((char*)d_ws + 512);        // 128 f32
  __bf16* WT  = (__bf16*)((char*)d_ws + 1024);      // 2 * 128*128 bf16 = 64 KB

  // empty segments must be exactly 0; memset re-zeroes every replay
  (void)hipMemsetAsync(out, 0, (size_t)NSEG * DIM * sizeof(float), stream);

  wt_kernel<<<64, 256, 0, stream>>>(W1, W2, WT);
  bias_kernel<<<1, 128, 0, stream>>>(b1, W2, b2, b1p, b2p);

  fused_kernel<<<N_TRIPLES / ROWS, 512, 0, stream>>>(dijk, seg, WT, b1p, b2p, out);
}

// Round 17
// 440.183 us; speedup vs baseline: 1.1713x; 1.1120x over previous
//
#include <hip/hip_runtime.h>
#include <hip/hip_bf16.h>
#include <cstdint>
#include <cstddef>

// CFnetFilter: w_ij = segment_sum(ssp(ssp(dijk@W1+b1)@W2+b2), seg_j)
//
// R17 = R12 (423us champion) at half tile / full occupancy, CORRECTED.
// (R16's bug: 4 waves x 16 cols covered only half the 128 columns.)
// Keep 512 threads = 8 waves x 16 cols (all 128 cols), tile = 64 rows,
// LDS 16 KB. Per-wave work halves: mt 0..3, acc[4] = 16 AGPR; per-wave
// regs ~57 <= 64 budget of __launch_bounds__(512,8) -> 8 waves/SIMD,
// 4 blocks/CU (64 KB LDS) = 100% occupancy vs R12's 75%. All else
// (16-col waves, 3-bit swizzle, base-2 softplus diet, hoisted addrs,
// paired-column reduce) R12-verbatim. Spill tell: WRITE_SIZE balloon.

typedef float  f32x4  __attribute__((ext_vector_type(4)));
typedef __bf16 bf16x8 __attribute__((ext_vector_type(8)));

// may_alias views for LDS type-punning (R5 lesson)
typedef uint32_t u32a    __attribute__((may_alias));
typedef bf16x8   bf16x8a __attribute__((may_alias));
typedef __bf16   bf16a   __attribute__((may_alias));

static constexpr int   N_TRIPLES = 2000000;
static constexpr int   DIM       = 128;
static constexpr int   NSEG      = 100000;
static constexpr int   ROWS      = 64;      // rows per block (2e6 / 64 exact)
static constexpr float LOG2F_    = 0.6931471805599453f;   // ln2
static constexpr float LOG2E_    = 1.4426950408889634f;   // 1/ln2

// base-2 softplus core: u = max(y,0) + log2(1 + 2^-|y|)
__device__ __forceinline__ float sp2_(float y) {
  float t = __builtin_amdgcn_exp2f(-__builtin_fabsf(y));   // v_exp with -abs mods
  return fmaxf(y, 0.0f) + __builtin_amdgcn_logf(1.0f + t); // v_log = log2
}

// WT1 = (W1*log2e)^T bf16 ; WT2 = W2^T bf16  (B-frags contiguous in k)
__global__ void wt_kernel(const float* __restrict__ W1, const float* __restrict__ W2,
                          __bf16* __restrict__ WT) {
  int t = blockIdx.x * 256 + threadIdx.x;   // 0..16383
  int k = t >> 7;
  int n = t & 127;
  WT[n * 128 + k]         = (__bf16)(W1[t] * LOG2E_);
  WT[16384 + n * 128 + k] = (__bf16)W2[t];
}

// b1p[n] = b1[n]*log2e ;  b2p[n] = (b2[n] - ln2*sum_k W2[k][n]) * log2e
__global__ void bias_kernel(const float* __restrict__ b1, const float* __restrict__ W2,
                            const float* __restrict__ b2,
                            float* __restrict__ b1p, float* __restrict__ b2p) {
  int n = threadIdx.x;
  float s = 0.0f;
  #pragma unroll 8
  for (int k = 0; k < 128; ++k) s += W2[k * 128 + n];
  b1p[n] = b1[n] * LOG2E_;
  b2p[n] = (b2[n] - LOG2F_ * s) * LOG2E_;
}

__global__ __launch_bounds__(512, 8) void fused_kernel(
    const float* __restrict__ dijk, const int* __restrict__ seg,
    const __bf16* __restrict__ WT,
    const float* __restrict__ b1v, const float* __restrict__ b2p,
    float* __restrict__ out)
{
  __shared__ __bf16 tile[ROWS * DIM];   // 16 KB: A, then u1, then wijk

  const int tid  = threadIdx.x;         // 0..511
  const int lane = tid & 63;
  const int wave = tid >> 6;            // 0..7 -> col slice [16w, 16w+16)
  const int l15  = lane & 15;
  const int g    = lane >> 4;           // k-group
  const int r0   = blockIdx.x * ROWS;

  char* tb = (char*)tile;

  // ---- phase 0: stage A = bf16(dijk rows) -> LDS (swizzled), cooperative ----
  // thread t: row = t>>3 (0..63), oct = t&7 (16 f32). 64 B/thread, coalesced.
  {
    int srow = tid >> 3, soct = tid & 7;
    const float* src = dijk + (size_t)(r0 + srow) * DIM + soct * 16;
    char* dst = tb + srow * 256;
    int swz = (srow & 7) << 4;
    f32x4 v0 = *(const f32x4*)(src);
    f32x4 v1 = *(const f32x4*)(src + 4);
    f32x4 v2 = *(const f32x4*)(src + 8);
    f32x4 v3 = *(const f32x4*)(src + 12);
    bf16x8 t8a, t8b;
    t8a[0]=(__bf16)v0[0]; t8a[1]=(__bf16)v0[1]; t8a[2]=(__bf16)v0[2]; t8a[3]=(__bf16)v0[3];
    t8a[4]=(__bf16)v1[0]; t8a[5]=(__bf16)v1[1]; t8a[6]=(__bf16)v1[2]; t8a[7]=(__bf16)v1[3];
    t8b[0]=(__bf16)v2[0]; t8b[1]=(__bf16)v2[1]; t8b[2]=(__bf16)v2[2]; t8b[3]=(__bf16)v2[3];
    t8b[4]=(__bf16)v3[0]; t8b[5]=(__bf16)v3[1]; t8b[6]=(__bf16)v3[2]; t8b[7]=(__bf16)v3[3];
    *(bf16x8a*)(dst + ((soct * 32)      ^ swz)) = t8a;
    *(bf16x8a*)(dst + ((soct * 32 + 16) ^ swz)) = t8b;
  }

  const int colw = wave * 16 + l15;       // this lane's output column
  const float bias1 = b1v[colw];
  const float bias2 = b2p[colw];

  // hoisted addressing (row&7 mt-invariant since 16 % 8 == 0):
  const int  swA = (l15 & 7) << 4;
  const char* abase = tb + l15 * 256;     // + mt*4096, mt = 0..3
  uint32_t bo[4];
  #pragma unroll
  for (int ks = 0; ks < 4; ++ks) bo[ks] = (uint32_t)((ks * 64 + g * 16) ^ swA);
  uint32_t wbase[4];
  #pragma unroll
  for (int j = 0; j < 4; ++j) {
    int rj = g * 4 + j;
    wbase[j] = (uint32_t)(rj * 256 + ((colw * 2) ^ ((rj & 7) << 4)));
  }

  __syncthreads();   // [1] A-tile complete

  // ---- phase 1: GEMM1 (reads A) ----
  f32x4 acc[4];
  {
    bf16x8 bf1[4];
    #pragma unroll
    for (int ks = 0; ks < 4; ++ks)
      bf1[ks] = *(const bf16x8*)(WT + colw * 128 + ks * 32 + g * 8);

    #pragma unroll
    for (int mt = 0; mt < 4; ++mt) acc[mt] = (f32x4){0.f, 0.f, 0.f, 0.f};
    #pragma unroll
    for (int mt = 0; mt < 4; ++mt) {
      const char* pm = abase + mt * 4096;
      #pragma unroll
      for (int ks = 0; ks < 4; ++ks) {
        bf16x8 a = *(const bf16x8a*)(pm + bo[ks]);
        acc[mt] = __builtin_amdgcn_mfma_f32_16x16x32_bf16(a, bf1[ks], acc[mt], 0, 0, 0);
      }
    }
  }

  __syncthreads();   // [2] all A-reads done -> tile reusable for u1

  // ---- phase 2: u1 = sp2(y1) -> tile (C/D: row = mt*16 + g*4 + j) ----
  #pragma unroll
  for (int mt = 0; mt < 4; ++mt) {
    #pragma unroll
    for (int j = 0; j < 4; ++j) {
      float u1 = sp2_(acc[mt][j] + bias1);
      *(bf16a*)(tb + wbase[j] + mt * 4096) = (__bf16)u1;
    }
  }

  __syncthreads();   // [3] u1 complete

  // ---- phase 3: GEMM2 (reads u1; W2 unscaled since ln2*log2e = 1) ----
  f32x4 acc2[4];
  {
    bf16x8 bf2[4];
    #pragma unroll
    for (int ks = 0; ks < 4; ++ks)
      bf2[ks] = *(const bf16x8*)(WT + 16384 + colw * 128 + ks * 32 + g * 8);

    #pragma unroll
    for (int mt = 0; mt < 4; ++mt) acc2[mt] = (f32x4){0.f, 0.f, 0.f, 0.f};
    #pragma unroll
    for (int mt = 0; mt < 4; ++mt) {
      const char* pm = abase + mt * 4096;
      #pragma unroll
      for (int ks = 0; ks < 4; ++ks) {
        bf16x8 a = *(const bf16x8a*)(pm + bo[ks]);
        acc2[mt] = __builtin_amdgcn_mfma_f32_16x16x32_bf16(a, bf2[ks], acc2[mt], 0, 0, 0);
      }
    }
  }

  __syncthreads();   // [4] all u1-reads done -> tile reusable for wijk

  // ---- phase 4: w = fma(sp2(y2), ln2, -ln2) -> tile ----
  #pragma unroll
  for (int mt = 0; mt < 4; ++mt) {
    #pragma unroll
    for (int j = 0; j < 4; ++j) {
      float u2 = sp2_(acc2[mt][j] + bias2);
      float wv = __builtin_fmaf(u2, LOG2F_, -LOG2F_);
      *(bf16a*)(tb + wbase[j] + mt * 4096) = (__bf16)wv;
    }
  }

  __syncthreads();   // [5] wijk complete, visible to all

  // ---- phase 5: segmented reduce (paired-column u32 form, 8-row chunks) ----
  // thread: col pair colb = (tid&63)*2, row group hh = tid>>6 -> 8 rows.
  {
    const int colb = (tid & 63) * 2;
    const int hh   = tid >> 6;           // 0..7
    const int rbeg = hh * 8;             // multiple of 8 -> row&7 = i
    const int* sp = seg + r0;
    const char* rbase = tb + rbeg * 256;
    const uint32_t cx = (uint32_t)(colb * 2);
    float a0 = 0.0f, a1 = 0.0f;
    int cur = sp[rbeg];
    #pragma unroll
    for (int i = 0; i < 8; ++i) {
      int s = sp[rbeg + i];
      if (s != cur) {
        atomicAdd(out + (size_t)cur * DIM + colb,     a0);
        atomicAdd(out + (size_t)cur * DIM + colb + 1, a1);
        a0 = 0.0f; a1 = 0.0f; cur = s;
      }
      uint32_t w = *(const u32a*)(rbase + i * 256 + (cx ^ (uint32_t)(i << 4)));
      a0 += __uint_as_float(w << 16);          // bf16 lo -> f32
      a1 += __uint_as_float(w & 0xffff0000u);  // bf16 hi -> f32
    }
    atomicAdd(out + (size_t)cur * DIM + colb,     a0);
    atomicAdd(out + (size_t)cur * DIM + colb + 1, a1);
  }
}

extern "C" void kernel_launch(void* const* d_in, const int* in_sizes, int n_in,
                              void* d_out, int out_size, void* d_ws, size_t ws_size,
                              hipStream_t stream) {
  const float* dijk = (const float*)d_in[0];
  const int*   seg  = (const int*)d_in[1];
  const float* W1   = (const float*)d_in[2];
  const float* b1   = (const float*)d_in[3];
  const float* W2   = (const float*)d_in[4];
  const float* b2   = (const float*)d_in[5];
  float* out = (float*)d_out;

  float*  b1p = (float*)d_ws;                       // 128 f32
  float*  b2p = (float*)((char*)d_ws + 512);        // 128 f32
  __bf16* WT  = (__bf16*)((char*)d_ws + 1024);      // 2 * 128*128 bf16 = 64 KB

  // empty segments must be exactly 0; memset re-zeroes every replay
  (void)hipMemsetAsync(out, 0, (size_t)NSEG * DIM * sizeof(float), stream);

  wt_kernel<<<64, 256, 0, stream>>>(W1, W2, WT);
  bias_kernel<<<1, 128, 0, stream>>>(b1, W2, b2, b1p, b2p);

  fused_kernel<<<N_TRIPLES / ROWS, 512, 0, stream>>>(dijk, seg, WT, b1p, b2p, out);
}

// Round 18
// 404.636 us; speedup vs baseline: 1.2742x; 1.0878x over previous
//
#include <hip/hip_runtime.h>
#include <hip/hip_bf16.h>
#include <cstdint>
#include <cstddef>

// CFnetFilter: w_ij = segment_sum(ssp(ssp(dijk@W1+b1)@W2+b2), seg_j)
//
// R18 = R12 (423us champion) + operand-swapped MFMA epilogue diet.
// Swap A<->B in both MFMAs (16x16x32 A/B fragment layouts are symmetric):
// D = WTslice . tile^T = y^T, so a lane's 4 C/D values per mt are 4
// CONSECUTIVE feature-columns of one data row -> contiguous 8 B in the
// row-major swizzled tile. Epilogue per 4 elements: 2x v_cvt_pk_bf16_f32
// + 1x ds_write_b64 (vs 4 cvt + 4 ds_write_b16). Stored layout bit-identical
// to R12 (same swizzle) -> GEMM2 reads (= old A-frag reads) and reduce
// untouched. Biases become 4 per-lane scalars (n = wave*16 + g*4 + j).
// Predicted ~-13% instruction count; wall tracks insts ~1:1 (R10-R17 books).

typedef float  f32x4  __attribute__((ext_vector_type(4)));
typedef __bf16 bf16x8 __attribute__((ext_vector_type(8)));
typedef uint32_t u32x2 __attribute__((ext_vector_type(2)));

// may_alias views for LDS type-punning (R5 lesson)
typedef uint32_t u32a    __attribute__((may_alias));
typedef u32x2    u32x2a  __attribute__((may_alias));
typedef bf16x8   bf16x8a __attribute__((may_alias));
typedef __bf16   bf16a   __attribute__((may_alias));

static constexpr int   N_TRIPLES = 2000000;
static constexpr int   DIM       = 128;
static constexpr int   NSEG      = 100000;
static constexpr int   ROWS      = 128;     // rows per block (2e6 / 128 exact)
static constexpr float LOG2F_    = 0.6931471805599453f;   // ln2
static constexpr float LOG2E_    = 1.4426950408889634f;   // 1/ln2

// base-2 softplus core: u = max(y,0) + log2(1 + 2^-|y|)
__device__ __forceinline__ float sp2_(float y) {
  float t = __builtin_amdgcn_exp2f(-__builtin_fabsf(y));   // v_exp with -abs mods
  return fmaxf(y, 0.0f) + __builtin_amdgcn_logf(1.0f + t); // v_log = log2
}

// packed f32x2 -> bf16x2 (RNE); low16 = a, high16 = b
__device__ __forceinline__ uint32_t cvtpk_(float a, float b) {
  uint32_t r;
  asm("v_cvt_pk_bf16_f32 %0, %1, %2" : "=v"(r) : "v"(a), "v"(b));
  return r;
}

// WT1 = (W1*log2e)^T bf16 ; WT2 = W2^T bf16  (frags contiguous in k)
__global__ void wt_kernel(const float* __restrict__ W1, const float* __restrict__ W2,
                          __bf16* __restrict__ WT) {
  int t = blockIdx.x * 256 + threadIdx.x;   // 0..16383
  int k = t >> 7;
  int n = t & 127;
  WT[n * 128 + k]         = (__bf16)(W1[t] * LOG2E_);
  WT[16384 + n * 128 + k] = (__bf16)W2[t];
}

// b1p[n] = b1[n]*log2e ;  b2p[n] = (b2[n] - ln2*sum_k W2[k][n]) * log2e
__global__ void bias_kernel(const float* __restrict__ b1, const float* __restrict__ W2,
                            const float* __restrict__ b2,
                            float* __restrict__ b1p, float* __restrict__ b2p) {
  int n = threadIdx.x;
  float s = 0.0f;
  #pragma unroll 8
  for (int k = 0; k < 128; ++k) s += W2[k * 128 + n];
  b1p[n] = b1[n] * LOG2E_;
  b2p[n] = (b2[n] - LOG2F_ * s) * LOG2E_;
}

__global__ __launch_bounds__(512, 6) void fused_kernel(
    const float* __restrict__ dijk, const int* __restrict__ seg,
    const __bf16* __restrict__ WT,
    const float* __restrict__ b1v, const float* __restrict__ b2p,
    float* __restrict__ out)
{
  __shared__ __bf16 tile[ROWS * DIM];   // 32 KB: A, then u1, then wijk

  const int tid  = threadIdx.x;         // 0..511
  const int lane = tid & 63;
  const int wave = tid >> 6;            // 0..7 -> feature slice [16w, 16w+16)
  const int l15  = lane & 15;
  const int g    = lane >> 4;           // k-group
  const int r0   = blockIdx.x * ROWS;

  char* tb = (char*)tile;

  // ---- phase 0: stage A = bf16(dijk rows) -> LDS (swizzled), cooperative ----
  {
    int row = tid >> 2, q = tid & 3;
    const float* src = dijk + (size_t)(r0 + row) * DIM + q * 32;
    char* dst = tb + row * 256;
    int swz = (row & 7) << 4;
    #pragma unroll
    for (int u = 0; u < 4; ++u) {
      f32x4 v0 = *(const f32x4*)(src + u * 8);
      f32x4 v1 = *(const f32x4*)(src + u * 8 + 4);
      bf16x8 t8;
      t8[0] = (__bf16)v0[0]; t8[1] = (__bf16)v0[1]; t8[2] = (__bf16)v0[2]; t8[3] = (__bf16)v0[3];
      t8[4] = (__bf16)v1[0]; t8[5] = (__bf16)v1[1]; t8[6] = (__bf16)v1[2]; t8[7] = (__bf16)v1[3];
      *(bf16x8a*)(dst + ((q * 64 + u * 16) ^ swz)) = t8;
    }
  }

  const int colw = wave * 16 + l15;       // WT row this lane supplies (A-frag)
  const int nb   = wave * 16 + g * 4;     // first feature col of this lane's C/D
  float bias1[4], bias2[4];
  #pragma unroll
  for (int j = 0; j < 4; ++j) {
    bias1[j] = b1v[nb + j];
    bias2[j] = b2p[nb + j];
  }

  // hoisted addressing (row&7 is mt-invariant since 16 % 8 == 0):
  // tile reads (B-frag now): row = mt*16 + l15, bytes (ks*64 + g*16) ^ swA
  const int  swA = (l15 & 7) << 4;
  const char* abase = tb + l15 * 256;     // + mt*4096
  uint32_t bo[4];
  #pragma unroll
  for (int ks = 0; ks < 4; ++ks) bo[ks] = (uint32_t)((ks * 64 + g * 16) ^ swA);
  // epilogue b64 stores: row = mt*16 + l15, feature bytes nb*2 (8B aligned)
  const uint32_t wsb = (uint32_t)(l15 * 256 + ((nb * 2) ^ swA));   // + mt*4096

  __syncthreads();   // [1] A-tile complete

  // ---- phase 1: GEMM1, swapped operands: D = WT1slice . A^T = y1^T ----
  f32x4 acc[8];
  {
    bf16x8 bf1[4];
    #pragma unroll
    for (int ks = 0; ks < 4; ++ks)
      bf1[ks] = *(const bf16x8*)(WT + colw * 128 + ks * 32 + g * 8);

    #pragma unroll
    for (int mt = 0; mt < 8; ++mt) acc[mt] = (f32x4){0.f, 0.f, 0.f, 0.f};
    #pragma unroll
    for (int mt = 0; mt < 8; ++mt) {
      const char* pm = abase + mt * 4096;
      #pragma unroll
      for (int ks = 0; ks < 4; ++ks) {
        bf16x8 a = *(const bf16x8a*)(pm + bo[ks]);
        acc[mt] = __builtin_amdgcn_mfma_f32_16x16x32_bf16(bf1[ks], a, acc[mt], 0, 0, 0);
      }
    }
  }

  __syncthreads();   // [2] all A-reads done -> tile reusable for u1

  // ---- phase 2: u1 = sp2(y1) -> tile; 4 contiguous features per b64 store ----
  #pragma unroll
  for (int mt = 0; mt < 8; ++mt) {
    float u0 = sp2_(acc[mt][0] + bias1[0]);
    float u1 = sp2_(acc[mt][1] + bias1[1]);
    float u2 = sp2_(acc[mt][2] + bias1[2]);
    float u3 = sp2_(acc[mt][3] + bias1[3]);
    u32x2 p;
    p[0] = cvtpk_(u0, u1);
    p[1] = cvtpk_(u2, u3);
    *(u32x2a*)(tb + wsb + mt * 4096) = p;
  }

  __syncthreads();   // [3] u1 complete

  // ---- phase 3: GEMM2, swapped operands (W2 unscaled; ln2*log2e = 1) ----
  f32x4 acc2[8];
  {
    bf16x8 bf2[4];
    #pragma unroll
    for (int ks = 0; ks < 4; ++ks)
      bf2[ks] = *(const bf16x8*)(WT + 16384 + colw * 128 + ks * 32 + g * 8);

    #pragma unroll
    for (int mt = 0; mt < 8; ++mt) acc2[mt] = (f32x4){0.f, 0.f, 0.f, 0.f};
    #pragma unroll
    for (int mt = 0; mt < 8; ++mt) {
      const char* pm = abase + mt * 4096;
      #pragma unroll
      for (int ks = 0; ks < 4; ++ks) {
        bf16x8 a = *(const bf16x8a*)(pm + bo[ks]);
        acc2[mt] = __builtin_amdgcn_mfma_f32_16x16x32_bf16(bf2[ks], a, acc2[mt], 0, 0, 0);
      }
    }
  }

  __syncthreads();   // [4] all u1-reads done -> tile reusable for wijk

  // ---- phase 4: w = fma(sp2(y2), ln2, -ln2) -> tile (b64 stores) ----
  #pragma unroll
  for (int mt = 0; mt < 8; ++mt) {
    float w0 = __builtin_fmaf(sp2_(acc2[mt][0] + bias2[0]), LOG2F_, -LOG2F_);
    float w1 = __builtin_fmaf(sp2_(acc2[mt][1] + bias2[1]), LOG2F_, -LOG2F_);
    float w2 = __builtin_fmaf(sp2_(acc2[mt][2] + bias2[2]), LOG2F_, -LOG2F_);
    float w3 = __builtin_fmaf(sp2_(acc2[mt][3] + bias2[3]), LOG2F_, -LOG2F_);
    u32x2 p;
    p[0] = cvtpk_(w0, w1);
    p[1] = cvtpk_(w2, w3);
    *(u32x2a*)(tb + wsb + mt * 4096) = p;
  }

  __syncthreads();   // [5] wijk complete, visible to all

  // ---- phase 5: segmented reduce (R12-verbatim, paired-column u32 form) ----
  {
    const int colb = (tid & 63) * 2;
    const int hh   = tid >> 6;           // 0..7
    const int rbeg = hh * 16;
    const int* sp = seg + r0;
    const char* rp[8];
    #pragma unroll
    for (int k = 0; k < 8; ++k)
      rp[k] = tb + rbeg * 256 + ((colb * 2) ^ (k << 4));
    float a0 = 0.0f, a1 = 0.0f;
    int cur = sp[rbeg];
    #pragma unroll
    for (int i = 0; i < 16; ++i) {
      int s = sp[rbeg + i];
      if (s != cur) {
        atomicAdd(out + (size_t)cur * DIM + colb,     a0);
        atomicAdd(out + (size_t)cur * DIM + colb + 1, a1);
        a0 = 0.0f; a1 = 0.0f; cur = s;
      }
      uint32_t w = *(const u32a*)(rp[i & 7] + i * 256);
      a0 += __uint_as_float(w << 16);          // bf16 lo -> f32
      a1 += __uint_as_float(w & 0xffff0000u);  // bf16 hi -> f32
    }
    atomicAdd(out + (size_t)cur * DIM + colb,     a0);
    atomicAdd(out + (size_t)cur * DIM + colb + 1, a1);
  }
}

extern "C" void kernel_launch(void* const* d_in, const int* in_sizes, int n_in,
                              void* d_out, int out_size, void* d_ws, size_t ws_size,
                              hipStream_t stream) {
  const float* dijk = (const float*)d_in[0];
  const int*   seg  = (const int*)d_in[1];
  const float* W1   = (const float*)d_in[2];
  const float* b1   = (const float*)d_in[3];
  const float* W2   = (const float*)d_in[4];
  const float* b2   = (const float*)d_in[5];
  float* out = (float*)d_out;

  float*  b1p = (float*)d_ws;                       // 128 f32
  float*  b2p = (float*)((char*)d_ws + 512);        // 128 f32
  __bf16* WT  = (__bf16*)((char*)d_ws + 1024);      // 2 * 128*128 bf16 = 64 KB

  // empty segments must be exactly 0; memset re-zeroes every replay
  (void)hipMemsetAsync(out, 0, (size_t)NSEG * DIM * sizeof(float), stream);

  wt_kernel<<<64, 256, 0, stream>>>(W1, W2, WT);
  bias_kernel<<<1, 128, 0, stream>>>(b1, W2, b2, b1p, b2p);

  fused_kernel<<<N_TRIPLES / ROWS, 512, 0, stream>>>(dijk, seg, WT, b1p, b2p, out);
}